// Round 3
// baseline (11616.144 us; speedup 1.0000x reference)
//
#include <hip/hip_runtime.h>
#include <hip/hip_bf16.h>

// LSTM T=512, B=64, I=H=512. Inputs/outputs are FP32 (per reference dtypes).
// CDNA4 has no fp32 MFMA -> convert W to bf16 once (prep kernel), convert x/h
// to bf16 fragments in-register, accumulate in fp32 MFMA, keep c in fp32.
// Round 3: correctness first; 512 per-step launches (launch-bound, optimize next).

typedef __attribute__((ext_vector_type(8))) short short8;  // 8 bf16 = 16 B
typedef __attribute__((ext_vector_type(4))) float f32x4;

#define T_STEPS 512
#define BATCH   64
#define HID     512
#define KIN     512
#define GATES   2048                 // 4*HID
#define BH      (BATCH * HID)        // 32768
#define WELEMS  (GATES * KIN)        // 1048576 per weight matrix

__device__ __forceinline__ float sigmoidf_fast(float x) {
    return 1.0f / (1.0f + __expf(-x));
}
__device__ __forceinline__ float tanhf_fast(float x) {
    return 2.0f / (1.0f + __expf(-2.0f * x)) - 1.0f;  // saturates correctly
}
__device__ __forceinline__ short f2bf(float f) {
    union { __hip_bfloat16 h; short s; } u;
    u.h = __float2bfloat16(f);
    return u.s;
}

// ---------------- prep: W fp32 -> bf16, bias combine, state init ----------------
__global__ __launch_bounds__(256) void prep(
    const float* __restrict__ W_ih, const float* __restrict__ W_hh,
    const float* __restrict__ b_ih, const float* __restrict__ b_hh,
    const float* __restrict__ h0,   const float* __restrict__ c0,
    short* __restrict__ Wih_bf, short* __restrict__ Whh_bf,
    float* __restrict__ bias,   short* __restrict__ hbuf0,
    float* __restrict__ cbuf)
{
    int i = blockIdx.x * 256 + threadIdx.x;
    if (i < WELEMS) {
        Wih_bf[i] = f2bf(W_ih[i]);
        Whh_bf[i] = f2bf(W_hh[i]);
    }
    if (i < GATES) bias[i] = b_ih[i] + b_hh[i];
    if (i < BH) {
        hbuf0[i] = f2bf(h0[i]);
        cbuf[i]  = c0[i];
    }
}

// ---------------- fused recurrent step ----------------
// 32 blocks x 256 thr = 128 waves; wave wg -> (mt = wg&3 batch tile, jt = wg>>2
// hidden-col tile). All 4 waves of a block share jt -> W tiles L1-reused.
// acc[g] (16x16) = x_t @ W_ih[g]^T + h_prev @ W_hh[g]^T ; then LSTM cell.
// MFMA 16x16x32 bf16. A/B frag: elem[row=lane&15][k=(lane>>4)*8+j];
// C/D: row=(lane>>4)*4+reg, col=lane&15 (m89-verified).
__global__ __launch_bounds__(256) void lstm_step_fused(
    const float* __restrict__ x_t,        // [64,512] fp32
    const short* __restrict__ Wih_bf,     // [2048,512] bf16
    const short* __restrict__ Whh_bf,     // [2048,512] bf16
    const float* __restrict__ bias,       // [2048] fp32 (b_ih+b_hh)
    const short* __restrict__ h_prev,     // [64,512] bf16
    short* __restrict__ h_next,           // [64,512] bf16
    float* __restrict__ c_buf,            // [64,512] fp32
    float* __restrict__ out_t)            // d_out + t*BH, fp32
{
    const int wave = threadIdx.x >> 6;
    const int lane = threadIdx.x & 63;
    const int quad = lane >> 4;
    const int lr   = lane & 15;
    const int wg   = blockIdx.x * 4 + wave;   // 0..127
    const int mt   = wg & 3;                  // batch tile 0..3
    const int jt   = wg >> 2;                 // hidden-col tile 0..31

    f32x4 acc[4];
#pragma unroll
    for (int g = 0; g < 4; ++g) acc[g] = (f32x4){0.f, 0.f, 0.f, 0.f};

    // ---- K-loop 1: x_t (fp32 -> bf16 in-register) @ W_ih^T ----
    {
        const float* aptr = x_t + (size_t)(mt * 16 + lr) * KIN + quad * 8;
        for (int k0 = 0; k0 < KIN; k0 += 32) {
            const float4 f0 = *reinterpret_cast<const float4*>(aptr + k0);
            const float4 f1 = *reinterpret_cast<const float4*>(aptr + k0 + 4);
            short8 a;
            a[0] = f2bf(f0.x); a[1] = f2bf(f0.y); a[2] = f2bf(f0.z); a[3] = f2bf(f0.w);
            a[4] = f2bf(f1.x); a[5] = f2bf(f1.y); a[6] = f2bf(f1.z); a[7] = f2bf(f1.w);
#pragma unroll
            for (int g = 0; g < 4; ++g) {
                const short* bptr =
                    Wih_bf + (size_t)(g * HID + jt * 16 + lr) * KIN + k0 + quad * 8;
                short8 b = *reinterpret_cast<const short8*>(bptr);
                acc[g] = __builtin_amdgcn_mfma_f32_16x16x32_bf16(a, b, acc[g], 0, 0, 0);
            }
        }
    }
    // ---- K-loop 2: h_prev (bf16) @ W_hh^T ----
    {
        const short* aptr = h_prev + (size_t)(mt * 16 + lr) * HID + quad * 8;
        for (int k0 = 0; k0 < HID; k0 += 32) {
            short8 a = *reinterpret_cast<const short8*>(aptr + k0);
#pragma unroll
            for (int g = 0; g < 4; ++g) {
                const short* bptr =
                    Whh_bf + (size_t)(g * HID + jt * 16 + lr) * HID + k0 + quad * 8;
                short8 b = *reinterpret_cast<const short8*>(bptr);
                acc[g] = __builtin_amdgcn_mfma_f32_16x16x32_bf16(a, b, acc[g], 0, 0, 0);
            }
        }
    }

    // ---- epilogue: bias + LSTM cell (c in fp32) ----
    const int j2 = jt * 16 + lr;
    const float bi = bias[0 * HID + j2];
    const float bf = bias[1 * HID + j2];
    const float bg = bias[2 * HID + j2];
    const float bo = bias[3 * HID + j2];

#pragma unroll
    for (int r = 0; r < 4; ++r) {
        const int b2 = mt * 16 + quad * 4 + r;
        const float i_ = sigmoidf_fast(acc[0][r] + bi);
        const float f_ = sigmoidf_fast(acc[1][r] + bf);
        const float g_ = tanhf_fast(acc[2][r] + bg);
        const float o_ = sigmoidf_fast(acc[3][r] + bo);

        const int cidx = b2 * HID + j2;
        const float c  = f_ * c_buf[cidx] + i_ * g_;
        c_buf[cidx] = c;
        const float h = o_ * tanhf_fast(c);
        h_next[cidx] = f2bf(h);
        out_t[cidx]  = h;
    }
}

// ---------------- finalize: hT = outputs[T-1], cT = cbuf ----------------
__global__ __launch_bounds__(256) void finalize(
    const float* __restrict__ last_out,   // d_out + (T-1)*BH
    const float* __restrict__ c_buf,
    float* __restrict__ out_tail)         // d_out + T*BH
{
    int i = blockIdx.x * 256 + threadIdx.x;
    if (i < BH) {
        out_tail[i]      = last_out[i];
        out_tail[BH + i] = c_buf[i];
    }
}

extern "C" void kernel_launch(void* const* d_in, const int* in_sizes, int n_in,
                              void* d_out, int out_size, void* d_ws, size_t ws_size,
                              hipStream_t stream) {
    const float* input = (const float*)d_in[0];
    const float* h0    = (const float*)d_in[1];
    const float* c0    = (const float*)d_in[2];
    const float* W_ih  = (const float*)d_in[3];
    const float* W_hh  = (const float*)d_in[4];
    const float* b_ih  = (const float*)d_in[5];
    const float* b_hh  = (const float*)d_in[6];
    float* out = (float*)d_out;

    // ws layout (~4.5 MB): Wih_bf | Whh_bf (short, WELEMS each) |
    //                      hbuf0 | hbuf1 (short, BH each) | cbuf fp32 BH | bias fp32 GATES
    char* ws = (char*)d_ws;
    short* Wih_bf = (short*)ws;
    short* Whh_bf = Wih_bf + WELEMS;
    short* hbuf0  = Whh_bf + WELEMS;
    short* hbuf1  = hbuf0 + BH;
    float* cbuf   = (float*)(hbuf1 + BH);
    float* bias   = cbuf + BH;

    prep<<<(WELEMS + 255) / 256, 256, 0, stream>>>(
        W_ih, W_hh, b_ih, b_hh, h0, c0,
        Wih_bf, Whh_bf, bias, hbuf0, cbuf);

    short* hb[2] = {hbuf0, hbuf1};
    for (int t = 0; t < T_STEPS; ++t) {
        lstm_step_fused<<<32, 256, 0, stream>>>(
            input + (size_t)t * BATCH * KIN,
            Wih_bf, Whh_bf, bias,
            hb[t & 1], hb[(t + 1) & 1], cbuf,
            out + (size_t)t * BH);
    }
    finalize<<<(BH + 255) / 256, 256, 0, stream>>>(
        out + (size_t)(T_STEPS - 1) * BH, cbuf, out + (size_t)T_STEPS * BH);
}

// Round 6
// 10538.070 us; speedup vs baseline: 1.1023x; 1.1023x over previous
//
#include <hip/hip_runtime.h>
#include <hip/hip_bf16.h>

// LSTM T=512, B=64, I=H=512, fp32 in/out, bf16 MFMA compute.
// Round 6: round-5 fence-protocol kernel, fixing the compile error only
// (__builtin_nontemporal_store needs an ext_vector type, not HIP float4).
//   producer: plain h stores -> __threadfence() -> __syncthreads() ->
//             tid0 fetch_add(bar[t], RELEASE, AGENT) -> nontemporal out stores
//   consumer: tid0 spin ACQUIRE/AGENT -> __syncthreads() -> __threadfence()
//             -> plain 16B h loads (fresh from coherent point)
// Structure: 32 blocks x 256 thr, block = j-tile (16 hidden cols x 4 gates),
// wave = batch-tile; A=W / B=x|h operand roles -> each lane owns (batch, j..j+3),
// c stays in VGPRs for all 512 steps; W_hh frags in LDS; W_ih frags L2-resident.

typedef __attribute__((ext_vector_type(8))) short short8;
typedef __attribute__((ext_vector_type(4))) float f32x4;

#define T_STEPS 512
#define BATCH   64
#define HID     512
#define GATES   2048
#define BH      (BATCH * HID)   // 32768
#define NBLOCKS 32
#define WCHUNKS (4 * 16 * 64)   // frag chunks per block-slice: g x kb x lane = 4096

__device__ __forceinline__ unsigned short f2bfu(float f) {
    union { __hip_bfloat16 h; unsigned short s; } u;
    u.h = __float2bfloat16(f);
    return u.s;
}
__device__ __forceinline__ float sigmoidf_fast(float x) {
    return 1.0f / (1.0f + __expf(-x));
}
__device__ __forceinline__ float tanhf_fast(float x) {
    return 2.0f / (1.0f + __expf(-2.0f * x)) - 1.0f;
}

// ---------------- prep: W fp32 -> bf16 fragment order; bias; h0; barriers ----------------
// Fragment layout: F[((jt*4+g)*16 + kb)*64 + lane][0..7] =
//   W[g*512 + jt*16 + (lane&15)][kb*32 + (lane>>4)*8 + j]
__global__ __launch_bounds__(256) void prep(
    const float* __restrict__ h0,
    const float* __restrict__ W_ih, const float* __restrict__ W_hh,
    const float* __restrict__ b_ih, const float* __restrict__ b_hh,
    unsigned short* __restrict__ WihF, unsigned short* __restrict__ WhhF,
    unsigned short* __restrict__ hbuf0, float* __restrict__ bias,
    int* __restrict__ bar)
{
    const int tid = blockIdx.x * 256 + threadIdx.x;   // grid covers [0, 262144)
    {
        const int which = (tid >= 131072);
        const int t2   = tid & 131071;
        const int lane = t2 & 63;
        const int kb   = (t2 >> 6) & 15;
        const int g    = (t2 >> 10) & 3;
        const int jt   = t2 >> 12;            // 0..31
        const float* W = which ? W_hh : W_ih;
        unsigned short* F = which ? WhhF : WihF;
        const int row = g * HID + jt * 16 + (lane & 15);
        const int k   = kb * 32 + (lane >> 4) * 8;
        const float* src = W + (size_t)row * HID + k;
        unsigned short* dst = F + ((((size_t)jt * 4 + g) * 16 + kb) * 64 + lane) * 8;
#pragma unroll
        for (int j = 0; j < 8; ++j) dst[j] = f2bfu(src[j]);
    }
    if (tid < GATES)   bias[tid]  = b_ih[tid] + b_hh[tid];
    if (tid < BH)      hbuf0[tid] = f2bfu(h0[tid]);
    if (tid < T_STEPS) bar[tid]   = 0;
}

// ---------------- persistent scan kernel ----------------
__global__ __launch_bounds__(256, 1) void lstm_persistent(
    const float* __restrict__ input,     // [512,64,512] fp32
    const float* __restrict__ c0,        // [64,512] fp32
    const unsigned short* __restrict__ WihF,
    const unsigned short* __restrict__ WhhF,
    const float* __restrict__ bias,
    unsigned short* __restrict__ hbuf,   // [2][BH] bf16
    int* __restrict__ bar,               // [T_STEPS]
    float* __restrict__ out)             // [T*BH | BH | BH] fp32
{
    __shared__ unsigned short WhhL[WCHUNKS * 8];   // 64 KB

    const int tid  = threadIdx.x;
    const int lane = tid & 63;
    const int bt   = tid >> 6;      // wave = batch tile 0..3
    const int jt   = blockIdx.x;    // j-tile 0..31
    const int quad = lane >> 4;
    const int lr   = lane & 15;

    // stage this block's W_hh fragment slice into LDS
    {
        const short8* src = reinterpret_cast<const short8*>(
            WhhF + (size_t)jt * WCHUNKS * 8);
        short8* dst = reinterpret_cast<short8*>(WhhL);
        for (int idx = tid; idx < WCHUNKS; idx += 256) dst[idx] = src[idx];
    }

    const int brow  = bt * 16 + lr;           // batch row of this lane's cells
    const int jbase = jt * 16 + quad * 4;     // first of 4 consecutive j columns
    float bs[4][4];
#pragma unroll
    for (int g = 0; g < 4; ++g)
#pragma unroll
        for (int r = 0; r < 4; ++r)
            bs[g][r] = bias[g * HID + jbase + r];

    f32x4 c = *reinterpret_cast<const f32x4*>(c0 + (size_t)brow * HID + jbase);

    __syncthreads();   // LDS staged

    const unsigned short* wih_lane = WihF + (size_t)jt * WCHUNKS * 8 + (size_t)lane * 8;
    float hlast[4];

    for (int t = 0; t < T_STEPS; ++t) {
        f32x4 acc[4];
#pragma unroll
        for (int g = 0; g < 4; ++g) acc[g] = (f32x4){0.f, 0.f, 0.f, 0.f};

        // ---- x-side (h-independent; overlaps the wait below) ----
        {
            const float* xp = input + ((size_t)t * BATCH + brow) * HID + quad * 8;
#pragma unroll
            for (int kb = 0; kb < 16; ++kb) {
                const f32x4 f0 = *reinterpret_cast<const f32x4*>(xp + kb * 32);
                const f32x4 f1 = *reinterpret_cast<const f32x4*>(xp + kb * 32 + 4);
                union { __hip_bfloat162 b2[4]; short8 s; } bu;
                bu.b2[0] = __float22bfloat162_rn(make_float2(f0.x, f0.y));
                bu.b2[1] = __float22bfloat162_rn(make_float2(f0.z, f0.w));
                bu.b2[2] = __float22bfloat162_rn(make_float2(f1.x, f1.y));
                bu.b2[3] = __float22bfloat162_rn(make_float2(f1.z, f1.w));
#pragma unroll
                for (int g = 0; g < 4; ++g) {
                    short8 afrag = *reinterpret_cast<const short8*>(
                        wih_lane + ((size_t)(g * 16 + kb) * 64) * 8);
                    acc[g] = __builtin_amdgcn_mfma_f32_16x16x32_bf16(afrag, bu.s, acc[g], 0, 0, 0);
                }
            }
        }

        // ---- wait for h_t (produced at step t-1) ----
        if (t > 0) {
            if (tid == 0) {
                while (__hip_atomic_load(&bar[t - 1], __ATOMIC_ACQUIRE,
                                         __HIP_MEMORY_SCOPE_AGENT) < NBLOCKS)
                    __builtin_amdgcn_s_sleep(2);
            }
            __syncthreads();
            __threadfence();   // invalidate -> fresh h from coherent point
        }

        // ---- h-side: plain 16B loads of h_prev ----
        {
            const short8* hp = reinterpret_cast<const short8*>(
                hbuf + (size_t)(t & 1) * BH + (size_t)brow * HID + quad * 8);
#pragma unroll
            for (int kb = 0; kb < 16; ++kb) {
                short8 hv = hp[kb * 4];   // stride 32 elems = 4 short8
#pragma unroll
                for (int g = 0; g < 4; ++g) {
                    short8 afrag = reinterpret_cast<const short8*>(WhhL)[(g * 16 + kb) * 64 + lane];
                    acc[g] = __builtin_amdgcn_mfma_f32_16x16x32_bf16(afrag, hv, acc[g], 0, 0, 0);
                }
            }
        }

        // ---- LSTM cell (c in registers) ----
        unsigned long long hpack = 0;
        f32x4 outv;
#pragma unroll
        for (int r = 0; r < 4; ++r) {
            const float i_ = sigmoidf_fast(acc[0][r] + bs[0][r]);
            const float f_ = sigmoidf_fast(acc[1][r] + bs[1][r]);
            const float g_ = tanhf_fast(acc[2][r] + bs[2][r]);
            const float o_ = sigmoidf_fast(acc[3][r] + bs[3][r]);
            const float cr = f_ * c[r] + i_ * g_;
            c[r] = cr;
            const float h = o_ * tanhf_fast(cr);
            hlast[r] = h;
            outv[r] = h;
            hpack |= (unsigned long long)f2bfu(h) << (16 * r);
        }

        // ---- publish h_{t+1}: plain store -> fence -> block barrier -> arrive ----
        *reinterpret_cast<unsigned long long*>(
            hbuf + (size_t)((t + 1) & 1) * BH + (size_t)brow * HID + jbase) = hpack;
        __threadfence();      // writeback: h visible at coherent point
        __syncthreads();      // all 4 waves' fences done
        if (t < T_STEPS - 1 && tid == 0)
            __hip_atomic_fetch_add(&bar[t], 1, __ATOMIC_RELEASE,
                                   __HIP_MEMORY_SCOPE_AGENT);

        // ---- out store (off critical path, nontemporal) ----
        __builtin_nontemporal_store(
            outv, reinterpret_cast<f32x4*>(out + ((size_t)t * BATCH + brow) * HID + jbase));
    }

    // tails: hT, cT from registers
    float* hT = out + (size_t)T_STEPS * BH;
    float* cT = hT + BH;
    f32x4 hv4;
#pragma unroll
    for (int r = 0; r < 4; ++r) hv4[r] = hlast[r];
    *reinterpret_cast<f32x4*>(hT + (size_t)brow * HID + jbase) = hv4;
    *reinterpret_cast<f32x4*>(cT + (size_t)brow * HID + jbase) = c;
}

extern "C" void kernel_launch(void* const* d_in, const int* in_sizes, int n_in,
                              void* d_out, int out_size, void* d_ws, size_t ws_size,
                              hipStream_t stream) {
    const float* input = (const float*)d_in[0];
    const float* h0    = (const float*)d_in[1];
    const float* c0    = (const float*)d_in[2];
    const float* W_ih  = (const float*)d_in[3];
    const float* W_hh  = (const float*)d_in[4];
    const float* b_ih  = (const float*)d_in[5];
    const float* b_hh  = (const float*)d_in[6];
    float* out = (float*)d_out;

    // ws layout (~4.4 MB): WihF | WhhF (bf16 frags, 2 MB each) | hbuf[2] bf16 |
    //                      bias fp32 | bar int[512]
    char* ws = (char*)d_ws;
    unsigned short* WihF = (unsigned short*)ws;
    unsigned short* WhhF = WihF + (size_t)GATES * HID;
    unsigned short* hbuf = WhhF + (size_t)GATES * HID;
    float* bias = (float*)(hbuf + 2 * BH);
    int* bar = (int*)(bias + GATES);

    prep<<<1024, 256, 0, stream>>>(h0, W_ih, W_hh, b_ih, b_hh,
                                   WihF, WhhF, hbuf, bias, bar);

    lstm_persistent<<<NBLOCKS, 256, 0, stream>>>(
        input, c0, WihF, WhhF, bias, hbuf, bar, out);
}

// Round 7
// 6921.892 us; speedup vs baseline: 1.6782x; 1.5224x over previous
//
#include <hip/hip_runtime.h>
#include <hip/hip_bf16.h>

// LSTM T=512, B=64, I=H=512, fp32 in/out, bf16 MFMA compute.
// Round 7: kill the per-step L2 wipe. Round 6's __threadfence() (device scope)
// = buffer_wbl2 + buffer_inv every step per block -> 396 MB HBM refetch,
// 20.8 us/step, latency-bound (MfmaUtil 0.5%). Only h (64 KB) and bar need
// cross-XCD coherence -> use SYSTEM-scope relaxed atomics (sc0 sc1: bypass
// L1+L2, hit the MALL coherence point directly), zero cache-maintenance ops.
//   producer: h stores (system relaxed, write-through) -> __threadfence_block()
//             (vmcnt drain only) -> __syncthreads -> tid0 fetch_add(system relaxed)
//   consumer: tid0 spin (system relaxed load) -> __syncthreads -> h loads
//             (system relaxed 8B pairs, fresh from MALL; stale L2 never consulted)
// W_ih/x/out keep normal cached paths -> L2 stays warm across all 512 steps.
// Structure unchanged: 32 blocks x 256 thr, block = j-tile, wave = batch-tile,
// A=W / B=x|h -> lane owns (batch, j..j+3), c in VGPRs; W_hh frags in LDS.

typedef __attribute__((ext_vector_type(8))) short short8;
typedef __attribute__((ext_vector_type(4))) float f32x4;

#define T_STEPS 512
#define BATCH   64
#define HID     512
#define GATES   2048
#define BH      (BATCH * HID)   // 32768
#define NBLOCKS 32
#define WCHUNKS (4 * 16 * 64)   // frag chunks per block-slice

__device__ __forceinline__ unsigned short f2bfu(float f) {
    union { __hip_bfloat16 h; unsigned short s; } u;
    u.h = __float2bfloat16(f);
    return u.s;
}
__device__ __forceinline__ float sigmoidf_fast(float x) {
    return 1.0f / (1.0f + __expf(-x));
}
__device__ __forceinline__ float tanhf_fast(float x) {
    return 2.0f / (1.0f + __expf(-2.0f * x)) - 1.0f;
}

// ---------------- prep: W fp32 -> bf16 fragment order; bias; h0; barriers ----------------
// F[((jt*4+g)*16 + kb)*64 + lane][0..7] =
//   W[g*512 + jt*16 + (lane&15)][kb*32 + (lane>>4)*8 + j]
__global__ __launch_bounds__(256) void prep(
    const float* __restrict__ h0,
    const float* __restrict__ W_ih, const float* __restrict__ W_hh,
    const float* __restrict__ b_ih, const float* __restrict__ b_hh,
    unsigned short* __restrict__ WihF, unsigned short* __restrict__ WhhF,
    unsigned short* __restrict__ hbuf0, float* __restrict__ bias,
    int* __restrict__ bar)
{
    const int tid = blockIdx.x * 256 + threadIdx.x;   // grid covers [0, 262144)
    {
        const int which = (tid >= 131072);
        const int t2   = tid & 131071;
        const int lane = t2 & 63;
        const int kb   = (t2 >> 6) & 15;
        const int g    = (t2 >> 10) & 3;
        const int jt   = t2 >> 12;            // 0..31
        const float* W = which ? W_hh : W_ih;
        unsigned short* F = which ? WhhF : WihF;
        const int row = g * HID + jt * 16 + (lane & 15);
        const int k   = kb * 32 + (lane >> 4) * 8;
        const float* src = W + (size_t)row * HID + k;
        unsigned short* dst = F + ((((size_t)jt * 4 + g) * 16 + kb) * 64 + lane) * 8;
#pragma unroll
        for (int j = 0; j < 8; ++j) dst[j] = f2bfu(src[j]);
    }
    if (tid < GATES)   bias[tid]  = b_ih[tid] + b_hh[tid];
    if (tid < BH)      hbuf0[tid] = f2bfu(h0[tid]);
    if (tid < T_STEPS) bar[tid]   = 0;
}

// ---------------- persistent scan kernel ----------------
__global__ __launch_bounds__(256, 1) void lstm_persistent(
    const float* __restrict__ input,     // [512,64,512] fp32
    const float* __restrict__ c0,        // [64,512] fp32
    const unsigned short* __restrict__ WihF,
    const unsigned short* __restrict__ WhhF,
    const float* __restrict__ bias,
    unsigned short* __restrict__ hbuf,   // [2][BH] bf16
    int* __restrict__ bar,               // [T_STEPS]
    float* __restrict__ out)             // [T*BH | BH | BH] fp32
{
    __shared__ unsigned short WhhL[WCHUNKS * 8];   // 64 KB

    const int tid  = threadIdx.x;
    const int lane = tid & 63;
    const int bt   = tid >> 6;      // wave = batch tile 0..3
    const int jt   = blockIdx.x;    // j-tile 0..31
    const int quad = lane >> 4;
    const int lr   = lane & 15;

    // stage this block's W_hh fragment slice into LDS
    {
        const short8* src = reinterpret_cast<const short8*>(
            WhhF + (size_t)jt * WCHUNKS * 8);
        short8* dst = reinterpret_cast<short8*>(WhhL);
        for (int idx = tid; idx < WCHUNKS; idx += 256) dst[idx] = src[idx];
    }

    const int brow  = bt * 16 + lr;           // batch row of this lane's cells
    const int jbase = jt * 16 + quad * 4;     // first of 4 consecutive j columns
    float bs[4][4];
#pragma unroll
    for (int g = 0; g < 4; ++g)
#pragma unroll
        for (int r = 0; r < 4; ++r)
            bs[g][r] = bias[g * HID + jbase + r];

    f32x4 c = *reinterpret_cast<const f32x4*>(c0 + (size_t)brow * HID + jbase);

    __syncthreads();   // LDS staged

    const unsigned short* wih_lane = WihF + (size_t)jt * WCHUNKS * 8 + (size_t)lane * 8;
    float hlast[4];

    for (int t = 0; t < T_STEPS; ++t) {
        f32x4 acc[4];
#pragma unroll
        for (int g = 0; g < 4; ++g) acc[g] = (f32x4){0.f, 0.f, 0.f, 0.f};

        // ---- x-side (h-independent; overlaps the wait below) ----
        {
            const float* xp = input + ((size_t)t * BATCH + brow) * HID + quad * 8;
#pragma unroll
            for (int kb = 0; kb < 16; ++kb) {
                const f32x4 f0 = *reinterpret_cast<const f32x4*>(xp + kb * 32);
                const f32x4 f1 = *reinterpret_cast<const f32x4*>(xp + kb * 32 + 4);
                union { __hip_bfloat162 b2[4]; short8 s; } bu;
                bu.b2[0] = __float22bfloat162_rn(make_float2(f0.x, f0.y));
                bu.b2[1] = __float22bfloat162_rn(make_float2(f0.z, f0.w));
                bu.b2[2] = __float22bfloat162_rn(make_float2(f1.x, f1.y));
                bu.b2[3] = __float22bfloat162_rn(make_float2(f1.z, f1.w));
#pragma unroll
                for (int g = 0; g < 4; ++g) {
                    short8 afrag = *reinterpret_cast<const short8*>(
                        wih_lane + ((size_t)(g * 16 + kb) * 64) * 8);
                    acc[g] = __builtin_amdgcn_mfma_f32_16x16x32_bf16(afrag, bu.s, acc[g], 0, 0, 0);
                }
            }
        }

        // ---- wait for h_t (produced at step t-1); no cache maintenance ----
        if (t > 0) {
            if (tid == 0) {
                while (__hip_atomic_load(&bar[t - 1], __ATOMIC_RELAXED,
                                         __HIP_MEMORY_SCOPE_SYSTEM) < NBLOCKS)
                    __builtin_amdgcn_s_sleep(1);
            }
            __syncthreads();
        }

        // ---- h-side: system-scope 8B loads (bypass L1+L2, read MALL) ----
        {
            const unsigned long long* hp = reinterpret_cast<const unsigned long long*>(
                hbuf + (size_t)(t & 1) * BH + (size_t)brow * HID + quad * 8);
#pragma unroll
            for (int kb = 0; kb < 16; ++kb) {
                unsigned long long lo = __hip_atomic_load(
                    hp + kb * 8, __ATOMIC_RELAXED, __HIP_MEMORY_SCOPE_SYSTEM);
                unsigned long long hi = __hip_atomic_load(
                    hp + kb * 8 + 1, __ATOMIC_RELAXED, __HIP_MEMORY_SCOPE_SYSTEM);
                union { unsigned long long u[2]; short8 s; } hv;
                hv.u[0] = lo; hv.u[1] = hi;
#pragma unroll
                for (int g = 0; g < 4; ++g) {
                    short8 afrag = reinterpret_cast<const short8*>(WhhL)[(g * 16 + kb) * 64 + lane];
                    acc[g] = __builtin_amdgcn_mfma_f32_16x16x32_bf16(afrag, hv.s, acc[g], 0, 0, 0);
                }
            }
        }

        // ---- LSTM cell (c in registers) ----
        unsigned long long hpack = 0;
        f32x4 outv;
#pragma unroll
        for (int r = 0; r < 4; ++r) {
            const float i_ = sigmoidf_fast(acc[0][r] + bs[0][r]);
            const float f_ = sigmoidf_fast(acc[1][r] + bs[1][r]);
            const float g_ = tanhf_fast(acc[2][r] + bs[2][r]);
            const float o_ = sigmoidf_fast(acc[3][r] + bs[3][r]);
            const float cr = f_ * c[r] + i_ * g_;
            c[r] = cr;
            const float h = o_ * tanhf_fast(cr);
            hlast[r] = h;
            outv[r] = h;
            hpack |= (unsigned long long)f2bfu(h) << (16 * r);
        }

        // ---- publish h_{t+1}: system-scope store -> vmcnt drain -> arrive ----
        __hip_atomic_store(reinterpret_cast<unsigned long long*>(
                               hbuf + (size_t)((t + 1) & 1) * BH + (size_t)brow * HID + jbase),
                           hpack, __ATOMIC_RELAXED, __HIP_MEMORY_SCOPE_SYSTEM);
        __threadfence_block();   // s_waitcnt vmcnt(0) lgkmcnt(0); no cache ops
        __syncthreads();         // all 4 waves drained
        if (t < T_STEPS - 1 && tid == 0)
            __hip_atomic_fetch_add(&bar[t], 1, __ATOMIC_RELAXED,
                                   __HIP_MEMORY_SCOPE_SYSTEM);

        // ---- out store (off critical path, nontemporal) ----
        __builtin_nontemporal_store(
            outv, reinterpret_cast<f32x4*>(out + ((size_t)t * BATCH + brow) * HID + jbase));
    }

    // tails: hT, cT from registers
    float* hT = out + (size_t)T_STEPS * BH;
    float* cT = hT + BH;
    f32x4 hv4;
#pragma unroll
    for (int r = 0; r < 4; ++r) hv4[r] = hlast[r];
    *reinterpret_cast<f32x4*>(hT + (size_t)brow * HID + jbase) = hv4;
    *reinterpret_cast<f32x4*>(cT + (size_t)brow * HID + jbase) = c;
}

extern "C" void kernel_launch(void* const* d_in, const int* in_sizes, int n_in,
                              void* d_out, int out_size, void* d_ws, size_t ws_size,
                              hipStream_t stream) {
    const float* input = (const float*)d_in[0];
    const float* h0    = (const float*)d_in[1];
    const float* c0    = (const float*)d_in[2];
    const float* W_ih  = (const float*)d_in[3];
    const float* W_hh  = (const float*)d_in[4];
    const float* b_ih  = (const float*)d_in[5];
    const float* b_hh  = (const float*)d_in[6];
    float* out = (float*)d_out;

    // ws layout (~4.4 MB): WihF | WhhF (bf16 frags, 2 MB each) | hbuf[2] bf16 |
    //                      bias fp32 | bar int[512]
    char* ws = (char*)d_ws;
    unsigned short* WihF = (unsigned short*)ws;
    unsigned short* WhhF = WihF + (size_t)GATES * HID;
    unsigned short* hbuf = WhhF + (size_t)GATES * HID;
    float* bias = (float*)(hbuf + 2 * BH);
    int* bar = (int*)(bias + GATES);

    prep<<<1024, 256, 0, stream>>>(h0, W_ih, W_hh, b_ih, b_hh,
                                   WihF, WhhF, hbuf, bias, bar);

    lstm_persistent<<<NBLOCKS, 256, 0, stream>>>(
        input, c0, WihF, WhhF, bias, hbuf, bar, out);
}